// Round 18
// baseline (165.738 us; speedup 1.0000x reference)
//
#include <hip/hip_runtime.h>
#include <hip/hip_bf16.h>

typedef __bf16 bf16x8 __attribute__((ext_vector_type(8)));
typedef __bf16 bf16x4 __attribute__((ext_vector_type(4)));
typedef float f32x4 __attribute__((ext_vector_type(4)));
typedef unsigned short u16x8 __attribute__((ext_vector_type(8)));
typedef short s16x4 __attribute__((ext_vector_type(4)));

// B=128, T=256, D=512, H=8, HD=64. M = B*T = 32768.

__device__ __forceinline__ unsigned short f2bf(float f) {
  unsigned u = __float_as_uint(f);
  u += 0x7fffu + ((u >> 16) & 1u);   // RNE
  return (unsigned short)(u >> 16);
}

__device__ __forceinline__ bf16x4 cvt4(f32x4 v) {
  bf16x4 o;
  o[0] = (__bf16)v[0]; o[1] = (__bf16)v[1]; o[2] = (__bf16)v[2]; o[3] = (__bf16)v[3];
  return o;
}

// K=16 bf16 MFMA: lane holds 4 elems at k=lg*4+j — matches pk[] layout exactly.
__device__ __forceinline__ f32x4 mfma16(bf16x4 a, bf16x4 b, f32x4 c) {
#if __has_builtin(__builtin_amdgcn_mfma_f32_16x16x16_bf16)
  return __builtin_amdgcn_mfma_f32_16x16x16_bf16(a, b, c, 0, 0, 0);
#elif __has_builtin(__builtin_amdgcn_mfma_f32_16x16x16bf16_1k)
  return __builtin_amdgcn_mfma_f32_16x16x16bf16_1k(
      __builtin_bit_cast(s16x4, a), __builtin_bit_cast(s16x4, b), c, 0, 0, 0);
#else
  f32x4 d = c;
  asm("v_mfma_f32_16x16x16_bf16 %0, %1, %2, %0" : "+v"(d) : "v"(a), "v"(b));
  return d;
#endif
}

// async global->LDS, 16B per lane. LDS dest wave-uniform; HW adds lane*16.
__device__ __forceinline__ void async16(const void* g, void* l) {
  __builtin_amdgcn_global_load_lds(
      (const __attribute__((address_space(1))) void*)g,
      (__attribute__((address_space(3))) void*)l, 16, 0, 0);
}

// ---------------- x fp32 -> bf16 (grid-stride, 2048 blocks) ----------------
__global__ __launch_bounds__(256) void k_convert_x(const float* __restrict__ in,
                                                   unsigned short* __restrict__ out) {
  for (int i = blockIdx.x * 256 + threadIdx.x; i < 2097152; i += 2048 * 256) {
    const float4* p = (const float4*)in + (size_t)i * 2;
    float4 a = p[0], b = p[1];
    u16x8 o;
    o[0] = f2bf(a.x); o[1] = f2bf(a.y); o[2] = f2bf(a.z); o[3] = f2bf(a.w);
    o[4] = f2bf(b.x); o[5] = f2bf(b.y); o[6] = f2bf(b.z); o[7] = f2bf(b.w);
    *((u16x8*)out + i) = o;
  }
}

// ---------------- all weight transposes in one launch ----------------
__global__ __launch_bounds__(256) void k_transpose_all(const float* __restrict__ Wq,
                                                       const float* __restrict__ Wk,
                                                       const float* __restrict__ Wv,
                                                       const float* __restrict__ Wo,
                                                       unsigned short* __restrict__ Wqkv,
                                                       unsigned short* __restrict__ Wot) {
  __shared__ unsigned short tile[64][72];
  int z = blockIdx.z;
  const float* inb;
  unsigned short* outb;
  int incols, c0;
  if (z < 3) {
    const float* w = (z == 0) ? Wq : (z == 1 ? Wk : Wv);
    inb = w + (size_t)blockIdx.x * 512 * 64;
    outb = Wqkv + ((size_t)z * 8 + blockIdx.x) * 32768;
    incols = 64; c0 = 0;
  } else {
    inb = Wo; outb = Wot; incols = 512; c0 = blockIdx.x * 64;
  }
  int r0 = blockIdx.y * 64;
  int tid = threadIdx.x;
  int r = tid >> 2, cq = (tid & 3) * 16;
  const float* src = inb + (size_t)(r0 + r) * incols + c0 + cq;
#pragma unroll
  for (int i = 0; i < 16; i += 4) {
    float4 v = *(const float4*)(src + i);
    tile[r][cq + i + 0] = f2bf(v.x);
    tile[r][cq + i + 1] = f2bf(v.y);
    tile[r][cq + i + 2] = f2bf(v.z);
    tile[r][cq + i + 3] = f2bf(v.w);
  }
  __syncthreads();
  int cr = tid >> 2, rq = (tid & 3) * 16;
  u16x8 o0, o1;
#pragma unroll
  for (int i = 0; i < 8; ++i) o0[i] = tile[rq + i][cr];
#pragma unroll
  for (int i = 0; i < 8; ++i) o1[i] = tile[rq + 8 + i][cr];
  unsigned short* dst = outb + (size_t)(c0 + cr) * 512 + r0 + rq;
  *(u16x8*)dst = o0;
  *(u16x8*)(dst + 8) = o1;
}

// ---------------- 128x128x(K=512) GEMM — m97 geometry, 2-barrier, 3 blocks/CU ----------------
// 256 threads (4 waves, 2x2). LDS = A[128][64] + B[128][64] = 32 KiB single buffer.
// Per K-step: {reads+32 MFMA} -> barrier -> stage(kb+1) (8 async16) -> vmcnt(0) -> barrier.
// Exposed drains hidden by ~3 co-resident blocks (m114; guide: 128^2=912 TF for this loop).
// Staging map derived from DEST side: dest chunk (wid*4+j)*64+lane -> row wid*32+j*8+(lane>>3),
// src chunk (lane&7)^(lane>>3). Read: ch = (k32*4+lg)^(lr&7) retrieves k-slice lg exactly.
// KIND 0: x*Wqk^T -> Q,K [B,H,T,HD]; Q pre-scaled by 0.125*log2e. grid 2048.
// KIND 1: a*Wo^T + bo -> fp32 out. grid 1024.
// KIND 2: x*Wv^T -> V^T [B,H,HD,T]. grid 1024.
template <int KIND>
__global__ __launch_bounds__(256, 3) void k_gemmP(
    const unsigned short* __restrict__ A,
    const unsigned short* __restrict__ Bmat,
    unsigned short* __restrict__ O0,
    unsigned short* __restrict__ O1,
    const float* __restrict__ bo,
    float* __restrict__ outf) {
  __shared__ unsigned short smem[16384];   // 32 KiB: A[128][64] | B[128][64]
  const int P = (KIND == 0) ? 256 : 128;   // blocks per XCD
  int xcd = blockIdx.x & 7, g = blockIdx.x >> 3;
  int w = xcd * P + g;
  int mt, nt;
  if (KIND == 0) { mt = w >> 3; nt = w & 7; }   // nt-inner: A panel shared on-XCD
  else           { mt = w >> 2; nt = w & 3; }
  int m0 = mt * 128, n0 = nt * 128;
  int tid = threadIdx.x;
  int wid = tid >> 6, lane = tid & 63;
  int lr = lane & 15, lg = lane >> 4;
  int wm = wid >> 1, wn = wid & 1;

  int rowbase = wid * 32 + (lane >> 3);
  int schunk = (lane & 7) ^ (lane >> 3);   // inverse-swizzled source chunk (rule 21)
  auto stage = [&](int kb) {
#pragma unroll
    for (int j = 0; j < 4; ++j) {
      int row = rowbase + j * 8;
      async16(A + (size_t)(m0 + row) * 512 + kb * 64 + schunk * 8,
              smem + (wid * 4 + j) * 512);
      async16(Bmat + (size_t)(n0 + row) * 512 + kb * 64 + schunk * 8,
              smem + 8192 + (wid * 4 + j) * 512);
    }
  };
  auto lda = [&](int mi, int k32) -> bf16x8 {
    int row = wm * 64 + mi * 16 + lr;
    int ch = (k32 * 4 + lg) ^ (lr & 7);
    return *(const bf16x8*)&smem[row * 64 + ch * 8];
  };
  auto ldb = [&](int ni, int k32) -> bf16x8 {
    int row = wn * 64 + ni * 16 + lr;
    int ch = (k32 * 4 + lg) ^ (lr & 7);
    return *(const bf16x8*)&smem[8192 + row * 64 + ch * 8];
  };

  f32x4 acc[4][4];
#pragma unroll
  for (int mi = 0; mi < 4; ++mi)
#pragma unroll
    for (int ni = 0; ni < 4; ++ni) acc[mi][ni] = (f32x4){0.f, 0.f, 0.f, 0.f};

#define MF(dst, afrag, bfrag)                                                        \
  if constexpr (KIND == 2)                                                           \
    dst = __builtin_amdgcn_mfma_f32_16x16x32_bf16(afrag, bfrag, dst, 0, 0, 0);       \
  else                                                                               \
    dst = __builtin_amdgcn_mfma_f32_16x16x32_bf16(bfrag, afrag, dst, 0, 0, 0);

  stage(0);
  asm volatile("s_waitcnt vmcnt(0)" ::: "memory");
  __builtin_amdgcn_s_barrier();
  asm volatile("" ::: "memory");

#pragma unroll
  for (int kb = 0; kb < 8; ++kb) {
    bf16x8 a[4][2], b[4][2];
#pragma unroll
    for (int i = 0; i < 4; ++i) {
      a[i][0] = lda(i, 0); a[i][1] = lda(i, 1);
      b[i][0] = ldb(i, 0); b[i][1] = ldb(i, 1);
    }
    __builtin_amdgcn_s_setprio(1);
#pragma unroll
    for (int mi = 0; mi < 4; ++mi)
#pragma unroll
      for (int ni = 0; ni < 4; ++ni)
#pragma unroll
        for (int k = 0; k < 2; ++k) { MF(acc[mi][ni], a[mi][k], b[ni][k]); }
    __builtin_amdgcn_s_setprio(0);
    if (kb < 7) {
      // reads of this step are complete per-wave (consumed by MFMAs); sync, overwrite, sync
      __builtin_amdgcn_s_barrier();
      asm volatile("" ::: "memory");
      stage(kb + 1);
      asm volatile("s_waitcnt vmcnt(0)" ::: "memory");
      __builtin_amdgcn_s_barrier();
      asm volatile("" ::: "memory");
    }
  }
#undef MF

  // ---- epilogues ----
  // swapped (KIND 0/1): acc[mi][ni][r] = C[m = wm*64+mi*16+lr][n = wn*64+ni*16+lg*4+r]
  // normal  (KIND 2):   acc[mi][ni][r] = C[m = wm*64+mi*16+lg*4+r][n = wn*64+ni*16+lr]
  int bb = mt >> 1, t0 = (mt & 1) * 128;
  if constexpr (KIND == 0) {
    int z = n0 >> 9;
    if (z == 0) {
#pragma unroll
      for (int mi = 0; mi < 4; ++mi)
#pragma unroll
        for (int ni = 0; ni < 4; ++ni) acc[mi][ni] *= 0.18033688011112042f;
    }
    int h = ((n0 & 511) >> 6) + wn;          // wave owns one head
    unsigned short* outp = (z ? O1 : O0) + (size_t)(bb * 8 + h) * 16384;
#pragma unroll
    for (int ni = 0; ni < 4; ++ni) {
      int hd0 = ni * 16 + lg * 4;
#pragma unroll
      for (int mi = 0; mi < 4; ++mi) {
        int tq = t0 + wm * 64 + mi * 16 + lr;
        *(bf16x4*)&outp[(size_t)tq * 64 + hd0] = cvt4(acc[mi][ni]);
      }
    }
  } else if constexpr (KIND == 1) {
#pragma unroll
    for (int ni = 0; ni < 4; ++ni) {
      int nb = n0 + wn * 64 + ni * 16 + lg * 4;
      float4 b4 = *(const float4*)&bo[nb];
#pragma unroll
      for (int mi = 0; mi < 4; ++mi) {
        int mg = m0 + wm * 64 + mi * 16 + lr;
        float4 o;
        o.x = acc[mi][ni][0] + b4.x; o.y = acc[mi][ni][1] + b4.y;
        o.z = acc[mi][ni][2] + b4.z; o.w = acc[mi][ni][3] + b4.w;
        *(float4*)&outf[(size_t)mg * 512 + nb] = o;
      }
    }
  } else {
    int h = (n0 >> 6) + wn;
    unsigned short* outp = O0 + (size_t)(bb * 8 + h) * 16384;
#pragma unroll
    for (int ni = 0; ni < 4; ++ni) {
      int hd = ni * 16 + lr;
#pragma unroll
      for (int mi = 0; mi < 4; ++mi) {
        int tq = t0 + wm * 64 + mi * 16 + lg * 4;
        *(bf16x4*)&outp[(size_t)hd * 256 + tq] = cvt4(acc[mi][ni]);
      }
    }
  }
}

// ---------------- fused causal attention v6 (R12, unchanged): P in registers ----------------
__global__ __launch_bounds__(512, 4) void k_attn2(
    const unsigned short* __restrict__ Qb,
    const unsigned short* __restrict__ Kb,
    const unsigned short* __restrict__ Vtb,
    unsigned short* __restrict__ Ob) {  // [B,T,512] bf16 (concat heads)
  __shared__ unsigned short Ksh[256 * 72];   // 36864 B
  __shared__ unsigned short Vsh[64 * 260];   // 33280 B  (total 70144 -> 2 blocks/CU)
  int bh = blockIdx.x;
  int tid = threadIdx.x, wid = tid >> 6, lane = tid & 63, lr = lane & 15, lg = lane >> 4;
  int bb = bh >> 3, h = bh & 7;
  const unsigned short* Kg = Kb + (size_t)bh * 16384;
  const unsigned short* Vg = Vtb + (size_t)bh * 16384;
  int4 gk[4], gv[4];
#pragma unroll
  for (int j = 0; j < 4; ++j) {
    int c = tid + j * 512;
    gk[j] = *(const int4*)(Kg + c * 8);
    gv[j] = *(const int4*)(Vg + c * 8);
  }
  int ci0 = wid, ci1 = 15 - wid;
  const unsigned short* q0 = Qb + (size_t)bh * 16384 + (size_t)(ci0 * 16 + lr) * 64 + lg * 8;
  const unsigned short* q1 = Qb + (size_t)bh * 16384 + (size_t)(ci1 * 16 + lr) * 64 + lg * 8;
  bf16x8 bq0a = *(const bf16x8*)q0;
  bf16x8 bq0b = *(const bf16x8*)(q0 + 32);
  bf16x8 bq1a = *(const bf16x8*)q1;
  bf16x8 bq1b = *(const bf16x8*)(q1 + 32);
#pragma unroll
  for (int j = 0; j < 4; ++j) {
    int c = tid + j * 512;
    *(int4*)&Ksh[(c >> 3) * 72 + (c & 7) * 8] = gk[j];
    *(int4*)&Vsh[(c >> 5) * 260 + (c & 31) * 8] = gv[j];
  }
  __syncthreads();

  auto do_chunk = [&](int ci, bf16x8 bqa, bf16x8 bqb) {
    int t0 = ci * 16, trow = t0 + lr;
    int ntV = ci + 1;
    f32x4 acc[16];
#pragma unroll
    for (int nt = 0; nt < 16; ++nt)
      if (nt < ntV) {
        acc[nt] = (f32x4){0.f, 0.f, 0.f, 0.f};
        bf16x8 ak0 = *(const bf16x8*)&Ksh[(nt * 16 + lr) * 72 + lg * 8];
        acc[nt] = __builtin_amdgcn_mfma_f32_16x16x32_bf16(ak0, bqa, acc[nt], 0, 0, 0);
        bf16x8 ak1 = *(const bf16x8*)&Ksh[(nt * 16 + lr) * 72 + 32 + lg * 8];
        acc[nt] = __builtin_amdgcn_mfma_f32_16x16x32_bf16(ak1, bqb, acc[nt], 0, 0, 0);
      }
    float m0c = -3.0e38f, m1c = -3.0e38f;
#pragma unroll
    for (int nt = 0; nt < 16; ++nt)
      if (nt < ntV) {
        if (nt == ci) {
#pragma unroll
          for (int r = 0; r < 4; ++r) {
            float v = acc[nt][r];
            if (lg * 4 + r > lr) v = -1.0e30f;
            acc[nt][r] = v;
          }
        }
        m0c = fmaxf(m0c, fmaxf(acc[nt][0], acc[nt][1]));
        m1c = fmaxf(m1c, fmaxf(acc[nt][2], acc[nt][3]));
      }
    float m = fmaxf(m0c, m1c);
    m = fmaxf(m, __shfl_xor(m, 16));
    m = fmaxf(m, __shfl_xor(m, 32));
    float s4[4] = {0.f, 0.f, 0.f, 0.f};
    bf16x4 pk[16];
#pragma unroll
    for (int nt = 0; nt < 16; ++nt)
      if (nt < ntV) {
#pragma unroll
        for (int r = 0; r < 4; ++r) {
          float p = exp2f(acc[nt][r] - m);
          s4[r] += p;
          pk[nt][r] = (__bf16)p;
        }
      }
    float s = (s4[0] + s4[1]) + (s4[2] + s4[3]);
    s += __shfl_xor(s, 16);
    s += __shfl_xor(s, 32);
    float inv = 1.0f / s;
    f32x4 aco[4];
#pragma unroll
    for (int vt = 0; vt < 4; ++vt) aco[vt] = (f32x4){0.f, 0.f, 0.f, 0.f};
#pragma unroll
    for (int nt = 0; nt < 16; ++nt)
      if (nt < ntV) {
#pragma unroll
        for (int vt = 0; vt < 4; ++vt) {
          bf16x4 av = *(const bf16x4*)&Vsh[(vt * 16 + lr) * 260 + nt * 16 + lg * 4];
          aco[vt] = mfma16(av, pk[nt], aco[vt]);
        }
      }
    unsigned short* obase = Ob + (size_t)(bb * 256 + trow) * 512 + h * 64 + lg * 4;
#pragma unroll
    for (int vt = 0; vt < 4; ++vt) {
      bf16x4 ov;
#pragma unroll
      for (int r = 0; r < 4; ++r) ov[r] = (__bf16)(aco[vt][r] * inv);
      *(bf16x4*)(obase + vt * 16) = ov;
    }
  };

  do_chunk(ci0, bq0a, bq0b);
  do_chunk(ci1, bq1a, bq1b);
}

extern "C" void kernel_launch(void* const* d_in, const int* in_sizes, int n_in,
                              void* d_out, int out_size, void* d_ws, size_t ws_size,
                              hipStream_t stream) {
  (void)in_sizes; (void)n_in; (void)out_size; (void)ws_size;
  const float* x = (const float*)d_in[0];
  const float* Wq = (const float*)d_in[1];
  const float* Wk = (const float*)d_in[2];
  const float* Wv = (const float*)d_in[3];
  const float* Wo = (const float*)d_in[4];
  const float* bo = (const float*)d_in[5];
  float* out = (float*)d_out;
  char* ws = (char*)d_ws;
  const size_t MB = 1024 * 1024;
  unsigned short* Qb = (unsigned short*)(ws);             // 32 MB
  unsigned short* Kb = (unsigned short*)(ws + 32 * MB);   // 32 MB
  unsigned short* Vtb = (unsigned short*)(ws + 64 * MB);  // 32 MB
  unsigned short* xb = (unsigned short*)(ws + 96 * MB);   // 32 MB (reused as attn out)
  unsigned short* Wqkv = (unsigned short*)(ws + 128 * MB); // [1536][512] (Q,K,V head-major)
  unsigned short* Wot = Wqkv + 786432;

  hipLaunchKernelGGL(k_convert_x, dim3(2048), dim3(256), 0, stream, x, xb);
  hipLaunchKernelGGL(k_transpose_all, dim3(8, 8, 4), dim3(256), 0, stream,
                     Wq, Wk, Wv, Wo, Wqkv, Wot);
  // QK projection: B = [Wq^T;Wk^T] = [1024][512]
  hipLaunchKernelGGL((k_gemmP<0>), dim3(2048), dim3(256), 0, stream,
                     xb, Wqkv, Qb, Kb, (const float*)nullptr, (float*)nullptr);
  // V projection -> V^T
  hipLaunchKernelGGL((k_gemmP<2>), dim3(1024), dim3(256), 0, stream,
                     xb, Wqkv + 524288, Vtb, (unsigned short*)nullptr,
                     (const float*)nullptr, (float*)nullptr);
  hipLaunchKernelGGL(k_attn2, dim3(1024), dim3(512), 0, stream, Qb, Kb, Vtb, xb);
  hipLaunchKernelGGL((k_gemmP<1>), dim3(1024), dim3(256), 0, stream,
                     xb, Wqkv + 786432, (unsigned short*)nullptr, (unsigned short*)nullptr,
                     bo, out);
}

// Round 19
// 156.844 us; speedup vs baseline: 1.0567x; 1.0567x over previous
//
#include <hip/hip_runtime.h>
#include <hip/hip_bf16.h>

typedef __bf16 bf16x8 __attribute__((ext_vector_type(8)));
typedef __bf16 bf16x4 __attribute__((ext_vector_type(4)));
typedef float f32x4 __attribute__((ext_vector_type(4)));
typedef unsigned short u16x8 __attribute__((ext_vector_type(8)));
typedef short s16x4 __attribute__((ext_vector_type(4)));

// B=128, T=256, D=512, H=8, HD=64. M = B*T = 32768.

__device__ __forceinline__ unsigned short f2bf(float f) {
  unsigned u = __float_as_uint(f);
  u += 0x7fffu + ((u >> 16) & 1u);   // RNE
  return (unsigned short)(u >> 16);
}

__device__ __forceinline__ bf16x4 cvt4(f32x4 v) {
  bf16x4 o;
  o[0] = (__bf16)v[0]; o[1] = (__bf16)v[1]; o[2] = (__bf16)v[2]; o[3] = (__bf16)v[3];
  return o;
}

// K=16 bf16 MFMA: lane holds 4 elems at k=lg*4+j — matches pk[] layout exactly.
__device__ __forceinline__ f32x4 mfma16(bf16x4 a, bf16x4 b, f32x4 c) {
#if __has_builtin(__builtin_amdgcn_mfma_f32_16x16x16_bf16)
  return __builtin_amdgcn_mfma_f32_16x16x16_bf16(a, b, c, 0, 0, 0);
#elif __has_builtin(__builtin_amdgcn_mfma_f32_16x16x16bf16_1k)
  return __builtin_amdgcn_mfma_f32_16x16x16bf16_1k(
      __builtin_bit_cast(s16x4, a), __builtin_bit_cast(s16x4, b), c, 0, 0, 0);
#else
  f32x4 d = c;
  asm("v_mfma_f32_16x16x16_bf16 %0, %1, %2, %0" : "+v"(d) : "v"(a), "v"(b));
  return d;
#endif
}

// async global->LDS, 16B per lane. LDS dest wave-uniform; HW adds lane*16.
__device__ __forceinline__ void async16(const void* g, void* l) {
  __builtin_amdgcn_global_load_lds(
      (const __attribute__((address_space(1))) void*)g,
      (__attribute__((address_space(3))) void*)l, 16, 0, 0);
}

// ---------------- x fp32 -> bf16 (grid-stride, 2048 blocks) ----------------
__global__ __launch_bounds__(256) void k_convert_x(const float* __restrict__ in,
                                                   unsigned short* __restrict__ out) {
  for (int i = blockIdx.x * 256 + threadIdx.x; i < 2097152; i += 2048 * 256) {
    const float4* p = (const float4*)in + (size_t)i * 2;
    float4 a = p[0], b = p[1];
    u16x8 o;
    o[0] = f2bf(a.x); o[1] = f2bf(a.y); o[2] = f2bf(a.z); o[3] = f2bf(a.w);
    o[4] = f2bf(b.x); o[5] = f2bf(b.y); o[6] = f2bf(b.z); o[7] = f2bf(b.w);
    *((u16x8*)out + i) = o;
  }
}

// ---------------- all weight transposes in one launch ----------------
__global__ __launch_bounds__(256) void k_transpose_all(const float* __restrict__ Wq,
                                                       const float* __restrict__ Wk,
                                                       const float* __restrict__ Wv,
                                                       const float* __restrict__ Wo,
                                                       unsigned short* __restrict__ Wqkv,
                                                       unsigned short* __restrict__ Wot) {
  __shared__ unsigned short tile[64][72];
  int z = blockIdx.z;
  const float* inb;
  unsigned short* outb;
  int incols, c0;
  if (z < 3) {
    const float* w = (z == 0) ? Wq : (z == 1 ? Wk : Wv);
    inb = w + (size_t)blockIdx.x * 512 * 64;
    outb = Wqkv + ((size_t)z * 8 + blockIdx.x) * 32768;
    incols = 64; c0 = 0;
  } else {
    inb = Wo; outb = Wot; incols = 512; c0 = blockIdx.x * 64;
  }
  int r0 = blockIdx.y * 64;
  int tid = threadIdx.x;
  int r = tid >> 2, cq = (tid & 3) * 16;
  const float* src = inb + (size_t)(r0 + r) * incols + c0 + cq;
#pragma unroll
  for (int i = 0; i < 16; i += 4) {
    float4 v = *(const float4*)(src + i);
    tile[r][cq + i + 0] = f2bf(v.x);
    tile[r][cq + i + 1] = f2bf(v.y);
    tile[r][cq + i + 2] = f2bf(v.z);
    tile[r][cq + i + 3] = f2bf(v.w);
  }
  __syncthreads();
  int cr = tid >> 2, rq = (tid & 3) * 16;
  u16x8 o0, o1;
#pragma unroll
  for (int i = 0; i < 8; ++i) o0[i] = tile[rq + i][cr];
#pragma unroll
  for (int i = 0; i < 8; ++i) o1[i] = tile[rq + 8 + i][cr];
  unsigned short* dst = outb + (size_t)(c0 + cr) * 512 + r0 + rq;
  *(u16x8*)dst = o0;
  *(u16x8*)(dst + 8) = o1;
}

// ---------------- 256x256x(K=512) GEMM, 4-phase, minimal sync (R12/R15 proven engine) ----------------
// KIND 0: x*Wqk^T -> Q,K [B,H,T,HD]; Q pre-scaled by 0.125*log2e. grid 512.
// KIND 1: a*Wo^T + bo -> fp32 out. grid 256.
// KIND 2: x*Wv^T -> V^T [B,H,HD,T]. grid 256.
template <int KIND>
__global__ __launch_bounds__(512, 1) void k_gemmP(
    const unsigned short* __restrict__ A,
    const unsigned short* __restrict__ Bmat,
    unsigned short* __restrict__ O0,
    unsigned short* __restrict__ O1,
    const float* __restrict__ bo,
    float* __restrict__ outf) {
  __shared__ unsigned short smem[65536];   // 2 bufs x (A[256][64] | B[256][64])
  const int P = (KIND == 0) ? 64 : 32;     // blocks per XCD
  int xcd = blockIdx.x & 7, g = blockIdx.x >> 3;
  int w = xcd * P + g;
  int mt, nt;
  if (KIND == 0) { mt = w >> 2; nt = w & 3; }
  else           { mt = w >> 1; nt = w & 1; }
  int m0 = mt * 256, n0 = nt * 256;
  int tid = threadIdx.x;
  int wid = tid >> 6, lane = tid & 63;
  int lr = lane & 15, lg = lane >> 4;
  int wm = wid >> 2, wn = wid & 3;

  int srow_off = wid * 16 + (lane >> 3);
  int schunk = (lane & 7) ^ (lane >> 3);   // inverse-swizzled source chunk (rule 21)
  auto stageA = [&](int kb, int buf, int half) {
#pragma unroll
    for (int j = 0; j < 2; ++j) {
      int row = half * 128 + srow_off + j * 8;
      async16(A + (size_t)(m0 + row) * 512 + kb * 64 + schunk * 8,
              smem + buf * 32768 + half * 8192 + (wid * 2 + j) * 512);
    }
  };
  auto stageB = [&](int kb, int buf, int half) {
#pragma unroll
    for (int j = 0; j < 2; ++j) {
      int row = half * 128 + srow_off + j * 8;
      async16(Bmat + (size_t)(n0 + row) * 512 + kb * 64 + schunk * 8,
              smem + buf * 32768 + 16384 + half * 8192 + (wid * 2 + j) * 512);
    }
  };
  auto lda = [&](int buf, int mi, int k32) -> bf16x8 {
    int row = mi * 32 + wm * 16 + lr;
    int ch = (k32 * 4 + lg) ^ (lr & 7);
    return *(const bf16x8*)&smem[buf * 32768 + row * 64 + ch * 8];
  };
  auto ldb = [&](int buf, int ni, int k32) -> bf16x8 {
    int row = ni * 64 + wn * 16 + lr;
    int ch = (k32 * 4 + lg) ^ (lr & 7);
    return *(const bf16x8*)&smem[buf * 32768 + 16384 + row * 64 + ch * 8];
  };

  f32x4 acc[8][4];
#pragma unroll
  for (int mi = 0; mi < 8; ++mi)
#pragma unroll
    for (int ni = 0; ni < 4; ++ni) acc[mi][ni] = (f32x4){0.f, 0.f, 0.f, 0.f};

#define MF(dst, afrag, bfrag)                                                        \
  if constexpr (KIND == 2)                                                           \
    dst = __builtin_amdgcn_mfma_f32_16x16x32_bf16(afrag, bfrag, dst, 0, 0, 0);       \
  else                                                                               \
    dst = __builtin_amdgcn_mfma_f32_16x16x32_bf16(bfrag, afrag, dst, 0, 0, 0);

  // prologue: tile0 halves [A0,B0,A1,B1]; wait A0,B0 (leave A1,B1 in flight)
  stageA(0, 0, 0); stageB(0, 0, 0); stageA(0, 0, 1); stageB(0, 0, 1);
  asm volatile("s_waitcnt vmcnt(4)" ::: "memory");
  __builtin_amdgcn_s_barrier();
  asm volatile("" ::: "memory");

  bf16x8 a03[4][2], a47[4][2], b01[2][2], b23[2][2];
#pragma unroll
  for (int t = 0; t < 8; ++t) {
    int buf = t & 1, nbuf = buf ^ 1;
    const bool st = (t < 7);
    // ---- phase 1: read a03(A0)+b01(B0); stage A0(t+1); MFMA Q00 ----
#pragma unroll
    for (int mi = 0; mi < 4; ++mi) { a03[mi][0] = lda(buf, mi, 0); a03[mi][1] = lda(buf, mi, 1); }
#pragma unroll
    for (int ni = 0; ni < 2; ++ni) { b01[ni][0] = ldb(buf, ni, 0); b01[ni][1] = ldb(buf, ni, 1); }
    if (st) stageA(t + 1, nbuf, 0);
    asm volatile("" ::: "memory");
    __builtin_amdgcn_s_setprio(1);
#pragma unroll
    for (int mi = 0; mi < 4; ++mi)
#pragma unroll
      for (int ni = 0; ni < 2; ++ni)
#pragma unroll
        for (int k = 0; k < 2; ++k) { MF(acc[mi][ni], a03[mi][k], b01[ni][k]); }
    __builtin_amdgcn_s_setprio(0);
    if (st) asm volatile("s_waitcnt vmcnt(4)" ::: "memory");
    else    asm volatile("s_waitcnt vmcnt(2)" ::: "memory");
    __builtin_amdgcn_s_barrier();
    asm volatile("" ::: "memory");
    // ---- phase 2: read a47(A1); stage B0(t+1); MFMA Q10 ----
#pragma unroll
    for (int mi = 0; mi < 4; ++mi) { a47[mi][0] = lda(buf, mi + 4, 0); a47[mi][1] = lda(buf, mi + 4, 1); }
    if (st) stageB(t + 1, nbuf, 0);
    asm volatile("" ::: "memory");
    __builtin_amdgcn_s_setprio(1);
#pragma unroll
    for (int mi = 0; mi < 4; ++mi)
#pragma unroll
      for (int ni = 0; ni < 2; ++ni)
#pragma unroll
        for (int k = 0; k < 2; ++k) { MF(acc[mi + 4][ni], a47[mi][k], b01[ni][k]); }
    __builtin_amdgcn_s_setprio(0);
    if (st) asm volatile("s_waitcnt vmcnt(4)" ::: "memory");
    else    asm volatile("s_waitcnt vmcnt(0)" ::: "memory");
    __builtin_amdgcn_s_barrier();
    asm volatile("" ::: "memory");
    // ---- phase 3: read b23(B1); stage A1(t+1); MFMA Q11; NO vmcnt ----
#pragma unroll
    for (int ni = 0; ni < 2; ++ni) { b23[ni][0] = ldb(buf, ni + 2, 0); b23[ni][1] = ldb(buf, ni + 2, 1); }
    if (st) stageA(t + 1, nbuf, 1);
    asm volatile("" ::: "memory");
    __builtin_amdgcn_s_setprio(1);
#pragma unroll
    for (int mi = 0; mi < 4; ++mi)
#pragma unroll
      for (int ni = 0; ni < 2; ++ni)
#pragma unroll
        for (int k = 0; k < 2; ++k) { MF(acc[mi + 4][ni + 2], a47[mi][k], b23[ni][k]); }
    __builtin_amdgcn_s_setprio(0);
    __builtin_amdgcn_s_barrier();
    asm volatile("" ::: "memory");
    // ---- phase 4: stage B1(t+1); MFMA Q01; vmcnt(4) ----
    if (st) stageB(t + 1, nbuf, 1);
    asm volatile("" ::: "memory");
    __builtin_amdgcn_s_setprio(1);
#pragma unroll
    for (int mi = 0; mi < 4; ++mi)
#pragma unroll
      for (int ni = 0; ni < 2; ++ni)
#pragma unroll
        for (int k = 0; k < 2; ++k) { MF(acc[mi][ni + 2], a03[mi][k], b23[ni][k]); }
    __builtin_amdgcn_s_setprio(0);
    if (st) asm volatile("s_waitcnt vmcnt(4)" ::: "memory");
    __builtin_amdgcn_s_barrier();
    asm volatile("" ::: "memory");
  }
#undef MF

  // ---- epilogues ----
  if constexpr (KIND == 0) {
    int z = n0 >> 9;
    if (z == 0) {
#pragma unroll
      for (int mi = 0; mi < 8; ++mi)
#pragma unroll
        for (int ni = 0; ni < 4; ++ni) acc[mi][ni] *= 0.18033688011112042f;
    }
    int hbase = (n0 & 511) >> 6;
    int hd0 = wn * 16 + lg * 4;
#pragma unroll
    for (int ni = 0; ni < 4; ++ni) {
      unsigned short* outp = (z ? O1 : O0) + (size_t)(mt * 8 + hbase + ni) * 16384;
#pragma unroll
      for (int mi = 0; mi < 8; ++mi) {
        int tq = mi * 32 + wm * 16 + lr;
        *(bf16x4*)&outp[(size_t)tq * 64 + hd0] = cvt4(acc[mi][ni]);
      }
    }
  } else if constexpr (KIND == 1) {
#pragma unroll
    for (int ni = 0; ni < 4; ++ni) {
      int nb = n0 + ni * 64 + wn * 16 + lg * 4;
      float4 b4 = *(const float4*)&bo[nb];
#pragma unroll
      for (int mi = 0; mi < 8; ++mi) {
        int mg = m0 + mi * 32 + wm * 16 + lr;
        float4 o;
        o.x = acc[mi][ni][0] + b4.x; o.y = acc[mi][ni][1] + b4.y;
        o.z = acc[mi][ni][2] + b4.z; o.w = acc[mi][ni][3] + b4.w;
        *(float4*)&outf[(size_t)mg * 512 + nb] = o;
      }
    }
  } else {
    int hbase = n0 >> 6;
    int hd = wn * 16 + lr;
#pragma unroll
    for (int ni = 0; ni < 4; ++ni) {
      unsigned short* outp = O0 + (size_t)(mt * 8 + hbase + ni) * 16384;
#pragma unroll
      for (int mi = 0; mi < 8; ++mi) {
        int tq = mi * 32 + wm * 16 + lg * 4;
        *(bf16x4*)&outp[(size_t)hd * 256 + tq] = cvt4(acc[mi][ni]);
      }
    }
  }
}

// ---------------- fused causal attention v6 (R12, unchanged): P in registers ----------------
__global__ __launch_bounds__(512, 4) void k_attn2(
    const unsigned short* __restrict__ Qb,
    const unsigned short* __restrict__ Kb,
    const unsigned short* __restrict__ Vtb,
    unsigned short* __restrict__ Ob) {  // [B,T,512] bf16 (concat heads)
  __shared__ unsigned short Ksh[256 * 72];   // 36864 B
  __shared__ unsigned short Vsh[64 * 260];   // 33280 B  (total 70144 -> 2 blocks/CU)
  int bh = blockIdx.x;
  int tid = threadIdx.x, wid = tid >> 6, lane = tid & 63, lr = lane & 15, lg = lane >> 4;
  int bb = bh >> 3, h = bh & 7;
  const unsigned short* Kg = Kb + (size_t)bh * 16384;
  const unsigned short* Vg = Vtb + (size_t)bh * 16384;
  int4 gk[4], gv[4];
#pragma unroll
  for (int j = 0; j < 4; ++j) {
    int c = tid + j * 512;
    gk[j] = *(const int4*)(Kg + c * 8);
    gv[j] = *(const int4*)(Vg + c * 8);
  }
  int ci0 = wid, ci1 = 15 - wid;
  const unsigned short* q0 = Qb + (size_t)bh * 16384 + (size_t)(ci0 * 16 + lr) * 64 + lg * 8;
  const unsigned short* q1 = Qb + (size_t)bh * 16384 + (size_t)(ci1 * 16 + lr) * 64 + lg * 8;
  bf16x8 bq0a = *(const bf16x8*)q0;
  bf16x8 bq0b = *(const bf16x8*)(q0 + 32);
  bf16x8 bq1a = *(const bf16x8*)q1;
  bf16x8 bq1b = *(const bf16x8*)(q1 + 32);
#pragma unroll
  for (int j = 0; j < 4; ++j) {
    int c = tid + j * 512;
    *(int4*)&Ksh[(c >> 3) * 72 + (c & 7) * 8] = gk[j];
    *(int4*)&Vsh[(c >> 5) * 260 + (c & 31) * 8] = gv[j];
  }
  __syncthreads();

  auto do_chunk = [&](int ci, bf16x8 bqa, bf16x8 bqb) {
    int t0 = ci * 16, trow = t0 + lr;
    int ntV = ci + 1;
    f32x4 acc[16];
#pragma unroll
    for (int nt = 0; nt < 16; ++nt)
      if (nt < ntV) {
        acc[nt] = (f32x4){0.f, 0.f, 0.f, 0.f};
        bf16x8 ak0 = *(const bf16x8*)&Ksh[(nt * 16 + lr) * 72 + lg * 8];
        acc[nt] = __builtin_amdgcn_mfma_f32_16x16x32_bf16(ak0, bqa, acc[nt], 0, 0, 0);
        bf16x8 ak1 = *(const bf16x8*)&Ksh[(nt * 16 + lr) * 72 + 32 + lg * 8];
        acc[nt] = __builtin_amdgcn_mfma_f32_16x16x32_bf16(ak1, bqb, acc[nt], 0, 0, 0);
      }
    float m0c = -3.0e38f, m1c = -3.0e38f;
#pragma unroll
    for (int nt = 0; nt < 16; ++nt)
      if (nt < ntV) {
        if (nt == ci) {
#pragma unroll
          for (int r = 0; r < 4; ++r) {
            float v = acc[nt][r];
            if (lg * 4 + r > lr) v = -1.0e30f;
            acc[nt][r] = v;
          }
        }
        m0c = fmaxf(m0c, fmaxf(acc[nt][0], acc[nt][1]));
        m1c = fmaxf(m1c, fmaxf(acc[nt][2], acc[nt][3]));
      }
    float m = fmaxf(m0c, m1c);
    m = fmaxf(m, __shfl_xor(m, 16));
    m = fmaxf(m, __shfl_xor(m, 32));
    float s4[4] = {0.f, 0.f, 0.f, 0.f};
    bf16x4 pk[16];
#pragma unroll
    for (int nt = 0; nt < 16; ++nt)
      if (nt < ntV) {
#pragma unroll
        for (int r = 0; r < 4; ++r) {
          float p = exp2f(acc[nt][r] - m);
          s4[r] += p;
          pk[nt][r] = (__bf16)p;
        }
      }
    float s = (s4[0] + s4[1]) + (s4[2] + s4[3]);
    s += __shfl_xor(s, 16);
    s += __shfl_xor(s, 32);
    float inv = 1.0f / s;
    f32x4 aco[4];
#pragma unroll
    for (int vt = 0; vt < 4; ++vt) aco[vt] = (f32x4){0.f, 0.f, 0.f, 0.f};
#pragma unroll
    for (int nt = 0; nt < 16; ++nt)
      if (nt < ntV) {
#pragma unroll
        for (int vt = 0; vt < 4; ++vt) {
          bf16x4 av = *(const bf16x4*)&Vsh[(vt * 16 + lr) * 260 + nt * 16 + lg * 4];
          aco[vt] = mfma16(av, pk[nt], aco[vt]);
        }
      }
    unsigned short* obase = Ob + (size_t)(bb * 256 + trow) * 512 + h * 64 + lg * 4;
#pragma unroll
    for (int vt = 0; vt < 4; ++vt) {
      bf16x4 ov;
#pragma unroll
      for (int r = 0; r < 4; ++r) ov[r] = (__bf16)(aco[vt][r] * inv);
      *(bf16x4*)(obase + vt * 16) = ov;
    }
  };

  do_chunk(ci0, bq0a, bq0b);
  do_chunk(ci1, bq1a, bq1b);
}

extern "C" void kernel_launch(void* const* d_in, const int* in_sizes, int n_in,
                              void* d_out, int out_size, void* d_ws, size_t ws_size,
                              hipStream_t stream) {
  (void)in_sizes; (void)n_in; (void)out_size; (void)ws_size;
  const float* x = (const float*)d_in[0];
  const float* Wq = (const float*)d_in[1];
  const float* Wk = (const float*)d_in[2];
  const float* Wv = (const float*)d_in[3];
  const float* Wo = (const float*)d_in[4];
  const float* bo = (const float*)d_in[5];
  float* out = (float*)d_out;
  char* ws = (char*)d_ws;
  const size_t MB = 1024 * 1024;
  unsigned short* Qb = (unsigned short*)(ws);             // 32 MB
  unsigned short* Kb = (unsigned short*)(ws + 32 * MB);   // 32 MB
  unsigned short* Vtb = (unsigned short*)(ws + 64 * MB);  // 32 MB
  unsigned short* xb = (unsigned short*)(ws + 96 * MB);   // 32 MB (reused as attn out)
  unsigned short* Wqkv = (unsigned short*)(ws + 128 * MB); // [1536][512] (Q,K,V head-major)
  unsigned short* Wot = Wqkv + 786432;

  hipLaunchKernelGGL(k_convert_x, dim3(2048), dim3(256), 0, stream, x, xb);
  hipLaunchKernelGGL(k_transpose_all, dim3(8, 8, 4), dim3(256), 0, stream,
                     Wq, Wk, Wv, Wo, Wqkv, Wot);
  // QK projection: B = [Wq^T;Wk^T] = [1024][512]
  hipLaunchKernelGGL((k_gemmP<0>), dim3(512), dim3(512), 0, stream,
                     xb, Wqkv, Qb, Kb, (const float*)nullptr, (float*)nullptr);
  // V projection -> V^T
  hipLaunchKernelGGL((k_gemmP<2>), dim3(256), dim3(512), 0, stream,
                     xb, Wqkv + 524288, Vtb, (unsigned short*)nullptr,
                     (const float*)nullptr, (float*)nullptr);
  hipLaunchKernelGGL(k_attn2, dim3(1024), dim3(512), 0, stream, Qb, Kb, Vtb, xb);
  hipLaunchKernelGGL((k_gemmP<1>), dim3(256), dim3(512), 0, stream,
                     xb, Wqkv + 786432, (unsigned short*)nullptr, (unsigned short*)nullptr,
                     bo, out);
}